// Round 10
// baseline (175.423 us; speedup 1.0000x reference)
//
#include <hip/hip_runtime.h>
#include <hip/hip_bf16.h>

// B=8, T=4096, C=384, H=64 causal single-head attention. fp32 in/out.
//
// Round-10: load-balance fix. Round 9's occupancy=34% despite 32 resident
// waves/CU = CUs running dry under the triangular work distribution:
// round-robin dispatch pairs block c with c+256 on one CU, and the old
// longest-first map gave that CU qt=(63-j)+(31-j) = 94..32 tiles (3x skew).
// New map: bid<256 -> qt=63-(bid>>3), bid>=256 -> qt=(bid-256)>>3, pairing
// qt=(63-j) with qt=j => 66 tiles/CU constant. Pure permutation (safe).
//
//  k_frag layout: [rt=row/16][c8=col/8][i=row%16][j=col%8]   (bf16)
//  vt_frag layout: [st=row/64][dt=d/16][sc=s%64/8][i=d%16][j=s%8]

typedef __bf16 bf16x8 __attribute__((ext_vector_type(8)));
typedef float  f32x4  __attribute__((ext_vector_type(4)));

#define BB   8
#define TT   4096
#define CC   384
#define HH   64
#define NROW (BB*TT)       // 32768
// C^-0.5 * log2(e): fold softmax scale + exp2 conversion into q at projection
#define QSCALE (0.05103103630798288f * 1.4426950408889634f)

#if __has_builtin(__builtin_amdgcn_exp2f)
#define EXP2(x) __builtin_amdgcn_exp2f(x)
#else
#define EXP2(x) exp2f(x)
#endif

// Compiler memory fence + HW LDS drain: orders wave-local LDS write->read.
#define LDS_ROUNDTRIP_FENCE() __asm volatile("s_waitcnt lgkmcnt(0)" ::: "memory")

__device__ __forceinline__ unsigned short f2bf(float f) {
    __bf16 h = (__bf16)f;
    return __builtin_bit_cast(unsigned short, h);
}

// ---------------------------------------------------------------- kernel 1
// Wt[mat][h][c] = bf16(W[mat][c][h]), via LDS tile (coalesced both sides).
__global__ __launch_bounds__(256) void wtrans_kernel(
        const float* __restrict__ Wk,
        const float* __restrict__ Wq,
        const float* __restrict__ Wv,
        unsigned short* __restrict__ Wt) {
    __shared__ __align__(16) unsigned short tile[64][72];
    const float* Wm = (blockIdx.y == 0) ? Wk : ((blockIdx.y == 1) ? Wq : Wv);
    unsigned short* Wtm = Wt + blockIdx.y * (HH * CC);
    const int c0 = blockIdx.x * 64;
#pragma unroll
    for (int i = 0; i < 16; ++i) {
        int id = threadIdx.x + i * 256;         // 0..4095
        int c = id >> 6, h = id & 63;
        tile[c][h] = f2bf(Wm[(c0 + c) * HH + h]);   // coalesced read
    }
    __syncthreads();
#pragma unroll
    for (int i = 0; i < 16; ++i) {
        int id = threadIdx.x + i * 256;
        int h = id >> 6, c = id & 63;
        Wtm[h * CC + c0 + c] = tile[c][h];      // coalesced write
    }
}

// ---------------------------------------------------------------- kernel 2
// QKV projection: [32768,384]x[384,64] x3 with 16x16x32 bf16 MFMA.
// 512 thr = 2 wave-groups x 4 waves; group g accumulates c in [192g,192g+192),
// partials combined in LDS. k and vt written in MFMA fragment layouts.
__global__ __launch_bounds__(512) void qkv_kernel(
        const float* __restrict__ x,
        const unsigned short* __restrict__ Wt,     // [3][64][384] bf16
        unsigned short* __restrict__ q_ws,         // [32768][64] row-major, pre-scaled
        unsigned short* __restrict__ k_ws,         // fragment layout
        unsigned short* __restrict__ vt_ws) {      // fragment layout
    __shared__ __align__(16) f32x4 xacc[256 * 13];              // 53248 B
    __shared__ __align__(16) unsigned short vtile[64][72];      //  9216 B

    const int lane = threadIdx.x & 63;
    const int wv8  = threadIdx.x >> 6;     // 0..7
    const int grp  = wv8 >> 2;             // wave-group 0/1
    const int wg   = wv8 & 3;              // wave within group
    const int g256 = threadIdx.x & 255;    // thread id within group
    const int l15  = lane & 15;
    const int quad = lane >> 4;
    const int rb   = blockIdx.x * 64;
    const int row  = rb + wg * 16 + l15;           // A-frag m index

    f32x4 acc[3][4];
    const f32x4 zero = {0.f, 0.f, 0.f, 0.f};
#pragma unroll
    for (int m = 0; m < 3; ++m)
#pragma unroll
        for (int nt = 0; nt < 4; ++nt) acc[m][nt] = zero;

    const float* xrow = x + (long)row * CC + grp * 192;
#pragma unroll
    for (int ch = 0; ch < 3; ++ch) {
#pragma unroll
        for (int kg = 0; kg < 2; ++kg) {
            const int coff = ch * 64 + kg * 32 + quad * 8;      // within group's 192
            float4 u0 = *reinterpret_cast<const float4*>(xrow + coff);
            float4 u1 = *reinterpret_cast<const float4*>(xrow + coff + 4);
            bf16x8 a;
            a[0] = (__bf16)u0.x; a[1] = (__bf16)u0.y;
            a[2] = (__bf16)u0.z; a[3] = (__bf16)u0.w;
            a[4] = (__bf16)u1.x; a[5] = (__bf16)u1.y;
            a[6] = (__bf16)u1.z; a[7] = (__bf16)u1.w;
            const int gcoff = grp * 192 + coff;
#pragma unroll
            for (int m = 0; m < 3; ++m) {
                const unsigned short* wtm = Wt + m * (HH * CC);
#pragma unroll
                for (int nt = 0; nt < 4; ++nt) {
                    bf16x8 bfr = *reinterpret_cast<const bf16x8*>(
                        wtm + (nt * 16 + l15) * CC + gcoff);
                    acc[m][nt] = __builtin_amdgcn_mfma_f32_16x16x32_bf16(
                        a, bfr, acc[m][nt], 0, 0, 0);
                }
            }
        }
    }

    // combine the two groups' partials through LDS
    const int cidx = g256 * 13;
    if (grp == 1) {
#pragma unroll
        for (int m = 0; m < 3; ++m)
#pragma unroll
            for (int nt = 0; nt < 4; ++nt)
                xacc[cidx + m * 4 + nt] = acc[m][nt];
    }
    __syncthreads();

    if (grp == 0) {
#pragma unroll
        for (int m = 0; m < 3; ++m)
#pragma unroll
            for (int nt = 0; nt < 4; ++nt)
                acc[m][nt] += xacc[cidx + m * 4 + nt];

        // Epilogue. C-layout: acc[m][nt][r] = out[local row quad*4+r][h = nt*16+l15]
        const int rt = (rb >> 4) + wg;             // global 16-row tile index
#pragma unroll
        for (int nt = 0; nt < 4; ++nt) {
            const int h  = nt * 16 + l15;
            const int c8 = h >> 3;
            const int jj = h & 7;
#pragma unroll
            for (int r = 0; r < 4; ++r) {
                const int gr = rb + wg * 16 + quad * 4 + r;
                const int ii = quad * 4 + r;       // row within 16-tile
                k_ws[((rt * 8 + c8) * 16 + ii) * 8 + jj] = f2bf(acc[0][nt][r]);
                q_ws[gr * HH + h] = f2bf(acc[1][nt][r] * QSCALE);
                vtile[h][ii + wg * 16] = f2bf(acc[2][nt][r]);
            }
        }
    }
    __syncthreads();
    // vt fragment store: chunk id = (dt*8+sc)*16+ii, perfectly coalesced.
    {
        int id = threadIdx.x;                      // 0..511
        int dt = id >> 7, sc = (id >> 4) & 7, ii = id & 15;
        unsigned short* dst = vt_ws + (long)(rb >> 6) * 4096
                              + (dt * 8 + sc) * 128 + ii * 8;
        *reinterpret_cast<uint4*>(dst) =
            *reinterpret_cast<const uint4*>(&vtile[dt * 16 + ii][sc * 8]);
    }
}

// ---------------------------------------------------------------- kernel 3
// Flash attention, barrier-free k-loop, 1024 thr = 4 wave-groups x 4 waves.
// Group g handles k-tiles t = 4j+g independently; 3-round LDS merge at end.
// launch_bounds (1024,4): VGPR cap 128 (body fits in 64) — never raise the
// min-waves arg to force occupancy (round 8: allocator squeeze -> 1.5GB spill).
__global__ __launch_bounds__(1024, 4) void attn_kernel(
        const unsigned short* __restrict__ q_ws,
        const unsigned short* __restrict__ k_ws,   // fragment layout
        const unsigned short* __restrict__ vt_ws,  // fragment layout
        float* __restrict__ out) {
    // P: per-wave 16 rows x 64 s, stride 64, XOR-swizzled (s ^ (q&7)<<3).
    __shared__ __align__(16) unsigned short P_lds[16 * 16 * 64]; // 32768 B
    __shared__ __align__(16) float xchg[64 * 65];                // 16640 B
    __shared__ float mx1[64], lx1[64];

    const int lane = threadIdx.x & 63;
    const int wv16 = threadIdx.x >> 6;     // 0..15
    const int grp  = wv16 >> 2;            // wave-group 0..3
    const int wg   = wv16 & 3;             // wave within group
    const int l15  = lane & 15;
    const int quad = lane >> 4;

    const int bid = blockIdx.x;
    const int b   = bid & 7;               // aligns b with XCD (round-robin)
    // Balanced qt map: CU gets blocks c and c+256 -> qt=(63-j) and qt=j,
    // 66 tiles/CU constant (was 94..32 with pure longest-first).
    const int idx = (bid & 255) >> 3;      // 0..31
    const int qt  = (bid < 256) ? (63 - idx) : idx;
    const int qrow = qt * 64 + wg * 16 + l15;      // this lane's q column index

    // Q fragments (B-operand: n=q=l15, k=d=quad*8+j), pre-scaled in q_ws
    const unsigned short* qbase = q_ws + (b * TT + qrow) * HH;
    const bf16x8 qf0 = *reinterpret_cast<const bf16x8*>(qbase + quad * 8);
    const bf16x8 qf1 = *reinterpret_cast<const bf16x8*>(qbase + 32 + quad * 8);

    const f32x4 zero = {0.f, 0.f, 0.f, 0.f};
    f32x4 o[4];
#pragma unroll
    for (int dt = 0; dt < 4; ++dt) o[dt] = zero;
    float mprev = -1e30f, lsum = 0.f;

    const int pbase = wv16 * 1024 + l15 * 64;      // this lane's P row base
    const int pxor  = (l15 & 7) << 3;              // bank swizzle

    for (int t = grp; t <= qt; t += 4) {
        const int s0 = t * 64;
        const unsigned short* ktile = k_ws + ((long)((b * TT + s0) >> 4)) * 1024;
        const unsigned short* vtile = vt_ws + ((long)((b * TT + s0) >> 6)) * 4096;

        // K A-frags: lane reads rows s=st*16+l15, cols quad*8.. — coalesced 1KB/load
        bf16x8 ka0[4], ka1[4];
#pragma unroll
        for (int st = 0; st < 4; ++st) {
            ka0[st] = *reinterpret_cast<const bf16x8*>(
                ktile + ((st * 8 + quad) * 16 + l15) * 8);
            ka1[st] = *reinterpret_cast<const bf16x8*>(
                ktile + ((st * 8 + 4 + quad) * 16 + l15) * 8);
        }
        // V B-frags: lane reads d=dt*16+l15, s=quad*8.. / 32+quad*8..
        bf16x8 vb0[4], vb1[4];
#pragma unroll
        for (int dt = 0; dt < 4; ++dt) {
            vb0[dt] = *reinterpret_cast<const bf16x8*>(
                vtile + dt * 1024 + quad * 128 + l15 * 8);
            vb1[dt] = *reinterpret_cast<const bf16x8*>(
                vtile + dt * 1024 + (4 + quad) * 128 + l15 * 8);
        }

        // S^T = K * Q^T : M=s(64 -> 4 tiles), N=q(16), K=d(64 -> 2 frags)
        f32x4 sc[4];
#pragma unroll
        for (int st = 0; st < 4; ++st) {
            f32x4 z = zero;
            z = __builtin_amdgcn_mfma_f32_16x16x32_bf16(ka0[st], qf0, z, 0, 0, 0);
            z = __builtin_amdgcn_mfma_f32_16x16x32_bf16(ka1[st], qf1, z, 0, 0, 0);
            sc[st] = z;
        }

        // causal mask (diagonal tile only): row = s = st*16+quad*4+r, col = q
        if (t == qt) {
#pragma unroll
            for (int st = 0; st < 4; ++st)
#pragma unroll
                for (int r = 0; r < 4; ++r) {
                    int sg = s0 + st * 16 + quad * 4 + r;
                    if (sg > qrow) sc[st][r] = -1e30f;
                }
        }

        // online softmax (scores already in log2 domain)
        float mloc = -1e30f;
#pragma unroll
        for (int st = 0; st < 4; ++st)
#pragma unroll
            for (int r = 0; r < 4; ++r) mloc = fmaxf(mloc, sc[st][r]);
        mloc = fmaxf(mloc, __shfl_xor(mloc, 16));
        mloc = fmaxf(mloc, __shfl_xor(mloc, 32));
        const float mnew = fmaxf(mprev, mloc);
        // max update is rare in late tiles: skip rescale when no row changed
        const unsigned long long anych = __ballot(mnew > mprev);
        float alpha = 1.0f;
        if (anych) alpha = EXP2(mprev - mnew);

        float psum = 0.f;
#pragma unroll
        for (int st = 0; st < 4; ++st) {
            union { unsigned short us[4]; uint2 u2; } pk;
#pragma unroll
            for (int r = 0; r < 4; ++r) {
                float p = EXP2(sc[st][r] - mnew);
                psum += p;
                pk.us[r] = f2bf(p);
            }
            *reinterpret_cast<uint2*>(
                &P_lds[pbase + ((st * 16 + quad * 4) ^ pxor)]) = pk.u2;
        }
        psum += __shfl_xor(psum, 16);
        psum += __shfl_xor(psum, 32);
        lsum = lsum * alpha + psum;
        mprev = mnew;

        if (anych) {
            // rescale O accumulator: O rows are q = quad*4+r
            float ar[4];
#pragma unroll
            for (int r = 0; r < 4; ++r) ar[r] = __shfl(alpha, quad * 4 + r);
#pragma unroll
            for (int dt = 0; dt < 4; ++dt)
#pragma unroll
                for (int r = 0; r < 4; ++r) o[dt][r] *= ar[r];
        }

        LDS_ROUNDTRIP_FENCE();   // wave-local P write->read ordering

        bf16x8 pf0 = *reinterpret_cast<const bf16x8*>(
            &P_lds[pbase + ((quad * 8) ^ pxor)]);
        bf16x8 pf1 = *reinterpret_cast<const bf16x8*>(
            &P_lds[pbase + ((32 + quad * 8) ^ pxor)]);
#pragma unroll
        for (int dt = 0; dt < 4; ++dt) {
            o[dt] = __builtin_amdgcn_mfma_f32_16x16x32_bf16(pf0, vb0[dt], o[dt], 0, 0, 0);
            o[dt] = __builtin_amdgcn_mfma_f32_16x16x32_bf16(pf1, vb1[dt], o[dt], 0, 0, 0);
        }
    }

    // ---- 3-round sequential merge of groups 1..3 into group 0 ----
    for (int rr = 1; rr < 4; ++rr) {
        __syncthreads();
        if (grp == rr) {
            if (quad == 0) { mx1[wg * 16 + l15] = mprev; lx1[wg * 16 + l15] = lsum; }
#pragma unroll
            for (int dt = 0; dt < 4; ++dt)
#pragma unroll
                for (int r = 0; r < 4; ++r)
                    xchg[(wg * 16 + quad * 4 + r) * 65 + dt * 16 + l15] = o[dt][r];
        }
        __syncthreads();
        if (grp == 0) {
            // per-row merge weights (rows q = wg*16 + quad*4 + r)
#pragma unroll
            for (int r = 0; r < 4; ++r) {
                const int row = wg * 16 + quad * 4 + r;
                const float m0r = __shfl(mprev, quad * 4 + r);
                const float m1r = mx1[row];
                const float ms  = fmaxf(m0r, m1r);
                const float w0  = EXP2(m0r - ms);
                const float w1  = EXP2(m1r - ms);
#pragma unroll
                for (int dt = 0; dt < 4; ++dt)
                    o[dt][r] = o[dt][r] * w0 + xchg[row * 65 + dt * 16 + l15] * w1;
            }
            // update lane-held stats (lane's own row q = wg*16 + l15)
            const float m1l = mx1[wg * 16 + l15];
            const float msl = fmaxf(mprev, m1l);
            lsum = EXP2(mprev - msl) * lsum + EXP2(m1l - msl) * lx1[wg * 16 + l15];
            mprev = msl;
        }
    }

    if (grp == 0) {
        float rl[4];
#pragma unroll
        for (int r = 0; r < 4; ++r) rl[r] = 1.0f / __shfl(lsum, quad * 4 + r);
        const int orow = qt * 64 + wg * 16 + quad * 4;
#pragma unroll
        for (int dt = 0; dt < 4; ++dt)
#pragma unroll
            for (int r = 0; r < 4; ++r)
                out[(long)(b * TT + orow + r) * HH + dt * 16 + l15] = o[dt][r] * rl[r];
    }
}

// ---------------------------------------------------------------- launch
extern "C" void kernel_launch(void* const* d_in, const int* in_sizes, int n_in,
                              void* d_out, int out_size, void* d_ws, size_t ws_size,
                              hipStream_t stream) {
    const float* x  = (const float*)d_in[0];
    const float* Wk = (const float*)d_in[1];
    const float* Wq = (const float*)d_in[2];
    const float* Wv = (const float*)d_in[3];
    float* out = (float*)d_out;

    char* ws = (char*)d_ws;
    unsigned short* Wt    = (unsigned short*)(ws);                         // 147456 B
    unsigned short* q_ws  = (unsigned short*)(ws + 147456);                // 4 MiB
    unsigned short* k_ws  = (unsigned short*)(ws + 147456 + 4194304);      // 4 MiB
    unsigned short* vt_ws = (unsigned short*)(ws + 147456 + 2 * 4194304);  // 4 MiB

    wtrans_kernel<<<dim3(6, 3), 256, 0, stream>>>(Wk, Wq, Wv, Wt);
    qkv_kernel<<<NROW / 64, 512, 0, stream>>>(x, Wt, q_ws, k_ws, vt_ws);
    attn_kernel<<<(TT / 64) * BB, 1024, 0, stream>>>(q_ws, k_ws, vt_ws, out);
}

// Round 11
// 165.796 us; speedup vs baseline: 1.0581x; 1.0581x over previous
//
#include <hip/hip_runtime.h>
#include <hip/hip_bf16.h>

// B=8, T=4096, C=384, H=64 causal single-head attention. fp32 in/out.
//
// Round-11: scheduler-proof load balance. Two rounds of guessing the
// block->CU pairing failed (round 9: longest-first 51.5us occ 34%;
// round 10 "balanced" map regressed to 57.2us — consistent with (2j,2j+1)
// intra-XCD pairing, qt sums 125-4j). Fix: make work per block CONSTANT.
// Block (p,b) processes q-tile A=63-p then B=p sequentially: (64-p)+(p+1)
// = 65 k-tiles per block, identical for all 256 blocks (1 block/CU,
// 16 waves, 4-way split-K per phase -> ~17-iter chain). Phase A is merged
// and written out BEFORE phase B starts so the phase-local VGPR live set
// stays ~127 (<=128 required for 1024-thr blocks; rounds 5/8: never let
// launch_bounds squeeze the allocator into spilling).
//
//  k_frag layout: [rt=row/16][c8=col/8][i=row%16][j=col%8]   (bf16)
//  vt_frag layout: [st=row/64][dt=d/16][sc=s%64/8][i=d%16][j=s%8]

typedef __bf16 bf16x8 __attribute__((ext_vector_type(8)));
typedef float  f32x4  __attribute__((ext_vector_type(4)));

#define BB   8
#define TT   4096
#define CC   384
#define HH   64
#define NROW (BB*TT)       // 32768
// C^-0.5 * log2(e): fold softmax scale + exp2 conversion into q at projection
#define QSCALE (0.05103103630798288f * 1.4426950408889634f)

#if __has_builtin(__builtin_amdgcn_exp2f)
#define EXP2(x) __builtin_amdgcn_exp2f(x)
#else
#define EXP2(x) exp2f(x)
#endif

// Compiler memory fence + HW LDS drain: orders wave-local LDS write->read.
#define LDS_ROUNDTRIP_FENCE() __asm volatile("s_waitcnt lgkmcnt(0)" ::: "memory")

__device__ __forceinline__ unsigned short f2bf(float f) {
    __bf16 h = (__bf16)f;
    return __builtin_bit_cast(unsigned short, h);
}

// ---------------------------------------------------------------- kernel 1
// Wt[mat][h][c] = bf16(W[mat][c][h]), via LDS tile (coalesced both sides).
__global__ __launch_bounds__(256) void wtrans_kernel(
        const float* __restrict__ Wk,
        const float* __restrict__ Wq,
        const float* __restrict__ Wv,
        unsigned short* __restrict__ Wt) {
    __shared__ __align__(16) unsigned short tile[64][72];
    const float* Wm = (blockIdx.y == 0) ? Wk : ((blockIdx.y == 1) ? Wq : Wv);
    unsigned short* Wtm = Wt + blockIdx.y * (HH * CC);
    const int c0 = blockIdx.x * 64;
#pragma unroll
    for (int i = 0; i < 16; ++i) {
        int id = threadIdx.x + i * 256;         // 0..4095
        int c = id >> 6, h = id & 63;
        tile[c][h] = f2bf(Wm[(c0 + c) * HH + h]);   // coalesced read
    }
    __syncthreads();
#pragma unroll
    for (int i = 0; i < 16; ++i) {
        int id = threadIdx.x + i * 256;
        int h = id >> 6, c = id & 63;
        Wtm[h * CC + c0 + c] = tile[c][h];      // coalesced write
    }
}

// ---------------------------------------------------------------- kernel 2
// QKV projection: [32768,384]x[384,64] x3 with 16x16x32 bf16 MFMA.
// 512 thr = 2 wave-groups x 4 waves; group g accumulates c in [192g,192g+192),
// partials combined in LDS. k and vt written in MFMA fragment layouts.
__global__ __launch_bounds__(512) void qkv_kernel(
        const float* __restrict__ x,
        const unsigned short* __restrict__ Wt,     // [3][64][384] bf16
        unsigned short* __restrict__ q_ws,         // [32768][64] row-major, pre-scaled
        unsigned short* __restrict__ k_ws,         // fragment layout
        unsigned short* __restrict__ vt_ws) {      // fragment layout
    __shared__ __align__(16) f32x4 xacc[256 * 13];              // 53248 B
    __shared__ __align__(16) unsigned short vtile[64][72];      //  9216 B

    const int lane = threadIdx.x & 63;
    const int wv8  = threadIdx.x >> 6;     // 0..7
    const int grp  = wv8 >> 2;             // wave-group 0/1
    const int wg   = wv8 & 3;              // wave within group
    const int g256 = threadIdx.x & 255;    // thread id within group
    const int l15  = lane & 15;
    const int quad = lane >> 4;
    const int rb   = blockIdx.x * 64;
    const int row  = rb + wg * 16 + l15;           // A-frag m index

    f32x4 acc[3][4];
    const f32x4 zero = {0.f, 0.f, 0.f, 0.f};
#pragma unroll
    for (int m = 0; m < 3; ++m)
#pragma unroll
        for (int nt = 0; nt < 4; ++nt) acc[m][nt] = zero;

    const float* xrow = x + (long)row * CC + grp * 192;
#pragma unroll
    for (int ch = 0; ch < 3; ++ch) {
#pragma unroll
        for (int kg = 0; kg < 2; ++kg) {
            const int coff = ch * 64 + kg * 32 + quad * 8;      // within group's 192
            float4 u0 = *reinterpret_cast<const float4*>(xrow + coff);
            float4 u1 = *reinterpret_cast<const float4*>(xrow + coff + 4);
            bf16x8 a;
            a[0] = (__bf16)u0.x; a[1] = (__bf16)u0.y;
            a[2] = (__bf16)u0.z; a[3] = (__bf16)u0.w;
            a[4] = (__bf16)u1.x; a[5] = (__bf16)u1.y;
            a[6] = (__bf16)u1.z; a[7] = (__bf16)u1.w;
            const int gcoff = grp * 192 + coff;
#pragma unroll
            for (int m = 0; m < 3; ++m) {
                const unsigned short* wtm = Wt + m * (HH * CC);
#pragma unroll
                for (int nt = 0; nt < 4; ++nt) {
                    bf16x8 bfr = *reinterpret_cast<const bf16x8*>(
                        wtm + (nt * 16 + l15) * CC + gcoff);
                    acc[m][nt] = __builtin_amdgcn_mfma_f32_16x16x32_bf16(
                        a, bfr, acc[m][nt], 0, 0, 0);
                }
            }
        }
    }

    // combine the two groups' partials through LDS
    const int cidx = g256 * 13;
    if (grp == 1) {
#pragma unroll
        for (int m = 0; m < 3; ++m)
#pragma unroll
            for (int nt = 0; nt < 4; ++nt)
                xacc[cidx + m * 4 + nt] = acc[m][nt];
    }
    __syncthreads();

    if (grp == 0) {
#pragma unroll
        for (int m = 0; m < 3; ++m)
#pragma unroll
            for (int nt = 0; nt < 4; ++nt)
                acc[m][nt] += xacc[cidx + m * 4 + nt];

        // Epilogue. C-layout: acc[m][nt][r] = out[local row quad*4+r][h = nt*16+l15]
        const int rt = (rb >> 4) + wg;             // global 16-row tile index
#pragma unroll
        for (int nt = 0; nt < 4; ++nt) {
            const int h  = nt * 16 + l15;
            const int c8 = h >> 3;
            const int jj = h & 7;
#pragma unroll
            for (int r = 0; r < 4; ++r) {
                const int gr = rb + wg * 16 + quad * 4 + r;
                const int ii = quad * 4 + r;       // row within 16-tile
                k_ws[((rt * 8 + c8) * 16 + ii) * 8 + jj] = f2bf(acc[0][nt][r]);
                q_ws[gr * HH + h] = f2bf(acc[1][nt][r] * QSCALE);
                vtile[h][ii + wg * 16] = f2bf(acc[2][nt][r]);
            }
        }
    }
    __syncthreads();
    // vt fragment store: chunk id = (dt*8+sc)*16+ii, perfectly coalesced.
    {
        int id = threadIdx.x;                      // 0..511
        int dt = id >> 7, sc = (id >> 4) & 7, ii = id & 15;
        unsigned short* dst = vt_ws + (long)(rb >> 6) * 4096
                              + (dt * 8 + sc) * 128 + ii * 8;
        *reinterpret_cast<uint4*>(dst) =
            *reinterpret_cast<const uint4*>(&vtile[dt * 16 + ii][sc * 8]);
    }
}

// ---------------------------------------------------------------- kernel 3
// Flash attention. 256 blocks x 1024 thr; block (p,b) does q-tile A=63-p
// then B=p (65 k-tiles constant). 16 waves = 4 groups x 4 waves; group g
// takes tiles t = 4j+g of the current phase. Barrier-free k-loop; merge +
// store per phase (keeps live VGPRs ~127).
__global__ __launch_bounds__(1024, 4) void attn_kernel(
        const unsigned short* __restrict__ q_ws,
        const unsigned short* __restrict__ k_ws,   // fragment layout
        const unsigned short* __restrict__ vt_ws,  // fragment layout
        float* __restrict__ out) {
    // P: per-wave 16 rows x 64 s, stride 64, XOR-swizzled (s ^ (q&7)<<3).
    __shared__ __align__(16) unsigned short P_lds[16 * 16 * 64]; // 32768 B
    __shared__ __align__(16) float xchg[64 * 65];                // 16640 B
    __shared__ float mx1[64], lx1[64];

    const int lane = threadIdx.x & 63;
    const int wv16 = threadIdx.x >> 6;     // 0..15
    const int grp  = wv16 >> 2;            // wave-group 0..3
    const int wg   = wv16 & 3;             // wave within group
    const int l15  = lane & 15;
    const int quad = lane >> 4;

    const int bid = blockIdx.x;
    const int b   = bid & 7;               // batch <-> XCD affinity
    const int p   = bid >> 3;              // 0..31

    const f32x4 zero = {0.f, 0.f, 0.f, 0.f};
    const int pbase = wv16 * 1024 + l15 * 64;      // this lane's P row base
    const int pxor  = (l15 & 7) << 3;              // bank swizzle

    // -------- one k-tile of phase with q-tile `qt` --------
    auto do_tile = [&](int t, int qt, int qrow,
                       const bf16x8& qf0, const bf16x8& qf1,
                       f32x4* o, float& mprev, float& lsum) {
        const int s0 = t * 64;
        const unsigned short* ktile = k_ws + ((long)((b * TT + s0) >> 4)) * 1024;
        const unsigned short* vtile = vt_ws + ((long)((b * TT + s0) >> 6)) * 4096;

        bf16x8 ka0[4], ka1[4];
#pragma unroll
        for (int st = 0; st < 4; ++st) {
            ka0[st] = *reinterpret_cast<const bf16x8*>(
                ktile + ((st * 8 + quad) * 16 + l15) * 8);
            ka1[st] = *reinterpret_cast<const bf16x8*>(
                ktile + ((st * 8 + 4 + quad) * 16 + l15) * 8);
        }
        bf16x8 vb0[4], vb1[4];
#pragma unroll
        for (int dt = 0; dt < 4; ++dt) {
            vb0[dt] = *reinterpret_cast<const bf16x8*>(
                vtile + dt * 1024 + quad * 128 + l15 * 8);
            vb1[dt] = *reinterpret_cast<const bf16x8*>(
                vtile + dt * 1024 + (4 + quad) * 128 + l15 * 8);
        }

        f32x4 sc[4];
#pragma unroll
        for (int st = 0; st < 4; ++st) {
            f32x4 z = zero;
            z = __builtin_amdgcn_mfma_f32_16x16x32_bf16(ka0[st], qf0, z, 0, 0, 0);
            z = __builtin_amdgcn_mfma_f32_16x16x32_bf16(ka1[st], qf1, z, 0, 0, 0);
            sc[st] = z;
        }

        if (t == qt) {                    // causal mask, diagonal tile only
#pragma unroll
            for (int st = 0; st < 4; ++st)
#pragma unroll
                for (int r = 0; r < 4; ++r) {
                    int sg = s0 + st * 16 + quad * 4 + r;
                    if (sg > qrow) sc[st][r] = -1e30f;
                }
        }

        float mloc = -1e30f;
#pragma unroll
        for (int st = 0; st < 4; ++st)
#pragma unroll
            for (int r = 0; r < 4; ++r) mloc = fmaxf(mloc, sc[st][r]);
        mloc = fmaxf(mloc, __shfl_xor(mloc, 16));
        mloc = fmaxf(mloc, __shfl_xor(mloc, 32));
        const float mnew = fmaxf(mprev, mloc);
        const unsigned long long anych = __ballot(mnew > mprev);
        float alpha = 1.0f;
        if (anych) alpha = EXP2(mprev - mnew);

        float psum = 0.f;
#pragma unroll
        for (int st = 0; st < 4; ++st) {
            union { unsigned short us[4]; uint2 u2; } pk;
#pragma unroll
            for (int r = 0; r < 4; ++r) {
                float pv = EXP2(sc[st][r] - mnew);
                psum += pv;
                pk.us[r] = f2bf(pv);
            }
            *reinterpret_cast<uint2*>(
                &P_lds[pbase + ((st * 16 + quad * 4) ^ pxor)]) = pk.u2;
        }
        psum += __shfl_xor(psum, 16);
        psum += __shfl_xor(psum, 32);
        lsum = lsum * alpha + psum;
        mprev = mnew;

        if (anych) {
            float ar[4];
#pragma unroll
            for (int r = 0; r < 4; ++r) ar[r] = __shfl(alpha, quad * 4 + r);
#pragma unroll
            for (int dt = 0; dt < 4; ++dt)
#pragma unroll
                for (int r = 0; r < 4; ++r) o[dt][r] *= ar[r];
        }

        LDS_ROUNDTRIP_FENCE();   // wave-local P write->read ordering

        bf16x8 pf0 = *reinterpret_cast<const bf16x8*>(
            &P_lds[pbase + ((quad * 8) ^ pxor)]);
        bf16x8 pf1 = *reinterpret_cast<const bf16x8*>(
            &P_lds[pbase + ((32 + quad * 8) ^ pxor)]);
#pragma unroll
        for (int dt = 0; dt < 4; ++dt) {
            o[dt] = __builtin_amdgcn_mfma_f32_16x16x32_bf16(pf0, vb0[dt], o[dt], 0, 0, 0);
            o[dt] = __builtin_amdgcn_mfma_f32_16x16x32_bf16(pf1, vb1[dt], o[dt], 0, 0, 0);
        }
    };

    // -------- merge groups 1..3 into group 0, then store q-tile `qt` --------
    auto merge_store = [&](int qt, f32x4* o, float& mprev, float& lsum) {
        for (int rr = 1; rr < 4; ++rr) {
            __syncthreads();
            if (grp == rr) {
                if (quad == 0) { mx1[wg * 16 + l15] = mprev; lx1[wg * 16 + l15] = lsum; }
#pragma unroll
                for (int dt = 0; dt < 4; ++dt)
#pragma unroll
                    for (int r = 0; r < 4; ++r)
                        xchg[(wg * 16 + quad * 4 + r) * 65 + dt * 16 + l15] = o[dt][r];
            }
            __syncthreads();
            if (grp == 0) {
#pragma unroll
                for (int r = 0; r < 4; ++r) {
                    const int row = wg * 16 + quad * 4 + r;
                    const float m0r = __shfl(mprev, quad * 4 + r);
                    const float m1r = mx1[row];
                    const float ms  = fmaxf(m0r, m1r);
                    const float w0  = EXP2(m0r - ms);
                    const float w1  = EXP2(m1r - ms);
#pragma unroll
                    for (int dt = 0; dt < 4; ++dt)
                        o[dt][r] = o[dt][r] * w0 + xchg[row * 65 + dt * 16 + l15] * w1;
                }
                const float m1l = mx1[wg * 16 + l15];
                const float msl = fmaxf(mprev, m1l);
                lsum = EXP2(mprev - msl) * lsum + EXP2(m1l - msl) * lx1[wg * 16 + l15];
                mprev = msl;
            }
        }
        if (grp == 0) {
            float rl[4];
#pragma unroll
            for (int r = 0; r < 4; ++r) rl[r] = 1.0f / __shfl(lsum, quad * 4 + r);
            const int orow = qt * 64 + wg * 16 + quad * 4;
#pragma unroll
            for (int dt = 0; dt < 4; ++dt)
#pragma unroll
                for (int r = 0; r < 4; ++r)
                    out[(long)(b * TT + orow + r) * HH + dt * 16 + l15] = o[dt][r] * rl[r];
        }
        __syncthreads();   // xchg/mx1 reusable by next phase
    };

    // ---------------- phase A: q-tile 63-p ----------------
    {
        const int qt = 63 - p;
        const int qrow = qt * 64 + wg * 16 + l15;
        const unsigned short* qbase = q_ws + (b * TT + qrow) * HH;
        const bf16x8 qf0 = *reinterpret_cast<const bf16x8*>(qbase + quad * 8);
        const bf16x8 qf1 = *reinterpret_cast<const bf16x8*>(qbase + 32 + quad * 8);
        f32x4 o[4];
#pragma unroll
        for (int dt = 0; dt < 4; ++dt) o[dt] = zero;
        float mprev = -1e30f, lsum = 0.f;
        for (int t = grp; t <= qt; t += 4)
            do_tile(t, qt, qrow, qf0, qf1, o, mprev, lsum);
        merge_store(qt, o, mprev, lsum);
    }

    // ---------------- phase B: q-tile p ----------------
    {
        const int qt = p;
        const int qrow = qt * 64 + wg * 16 + l15;
        const unsigned short* qbase = q_ws + (b * TT + qrow) * HH;
        const bf16x8 qf0 = *reinterpret_cast<const bf16x8*>(qbase + quad * 8);
        const bf16x8 qf1 = *reinterpret_cast<const bf16x8*>(qbase + 32 + quad * 8);
        f32x4 o[4];
#pragma unroll
        for (int dt = 0; dt < 4; ++dt) o[dt] = zero;
        float mprev = -1e30f, lsum = 0.f;
        for (int t = grp; t <= qt; t += 4)
            do_tile(t, qt, qrow, qf0, qf1, o, mprev, lsum);
        merge_store(qt, o, mprev, lsum);
    }
}

// ---------------------------------------------------------------- launch
extern "C" void kernel_launch(void* const* d_in, const int* in_sizes, int n_in,
                              void* d_out, int out_size, void* d_ws, size_t ws_size,
                              hipStream_t stream) {
    const float* x  = (const float*)d_in[0];
    const float* Wk = (const float*)d_in[1];
    const float* Wq = (const float*)d_in[2];
    const float* Wv = (const float*)d_in[3];
    float* out = (float*)d_out;

    char* ws = (char*)d_ws;
    unsigned short* Wt    = (unsigned short*)(ws);                         // 147456 B
    unsigned short* q_ws  = (unsigned short*)(ws + 147456);                // 4 MiB
    unsigned short* k_ws  = (unsigned short*)(ws + 147456 + 4194304);      // 4 MiB
    unsigned short* vt_ws = (unsigned short*)(ws + 147456 + 2 * 4194304);  // 4 MiB

    wtrans_kernel<<<dim3(6, 3), 256, 0, stream>>>(Wk, Wq, Wv, Wt);
    qkv_kernel<<<NROW / 64, 512, 0, stream>>>(x, Wt, q_ws, k_ws, vt_ws);
    attn_kernel<<<(TT / 128) * BB, 1024, 0, stream>>>(q_ws, k_ws, vt_ws, out);
}

// Round 12
// 164.634 us; speedup vs baseline: 1.0655x; 1.0071x over previous
//
#include <hip/hip_runtime.h>
#include <hip/hip_bf16.h>

// B=8, T=4096, C=384, H=64 causal single-head attention. fp32 in/out.
//
// Round-12: qkv MLP fix. Round 11 exposed qkv as #1 (48us, MfmaUtil 3.4%,
// VALUBusy 3.3%, HBM 800 GB/s, VGPR 56): latency-bound with ~2 outstanding
// loads/wave (Little's law: 800 GB/s x 375ns = 1.2 KB/CU in flight). Fix:
// hoist all 12 float4 x-loads per lane to the top (12 independent loads in
// flight), then convert, then the 72-MFMA loop (Wt is L1-resident, 3 KB/step
// shared by 8 waves). Live set ~111 VGPR -> (512,4) cap 128 is calculated,
// not a squeeze. attn/wtrans unchanged from round 11 (single variable).
//
//  k_frag layout: [rt=row/16][c8=col/8][i=row%16][j=col%8]   (bf16)
//  vt_frag layout: [st=row/64][dt=d/16][sc=s%64/8][i=d%16][j=s%8]

typedef __bf16 bf16x8 __attribute__((ext_vector_type(8)));
typedef float  f32x4  __attribute__((ext_vector_type(4)));

#define BB   8
#define TT   4096
#define CC   384
#define HH   64
#define NROW (BB*TT)       // 32768
// C^-0.5 * log2(e): fold softmax scale + exp2 conversion into q at projection
#define QSCALE (0.05103103630798288f * 1.4426950408889634f)

#if __has_builtin(__builtin_amdgcn_exp2f)
#define EXP2(x) __builtin_amdgcn_exp2f(x)
#else
#define EXP2(x) exp2f(x)
#endif

// Compiler memory fence + HW LDS drain: orders wave-local LDS write->read.
#define LDS_ROUNDTRIP_FENCE() __asm volatile("s_waitcnt lgkmcnt(0)" ::: "memory")

__device__ __forceinline__ unsigned short f2bf(float f) {
    __bf16 h = (__bf16)f;
    return __builtin_bit_cast(unsigned short, h);
}

// ---------------------------------------------------------------- kernel 1
// Wt[mat][h][c] = bf16(W[mat][c][h]), via LDS tile (coalesced both sides).
__global__ __launch_bounds__(256) void wtrans_kernel(
        const float* __restrict__ Wk,
        const float* __restrict__ Wq,
        const float* __restrict__ Wv,
        unsigned short* __restrict__ Wt) {
    __shared__ __align__(16) unsigned short tile[64][72];
    const float* Wm = (blockIdx.y == 0) ? Wk : ((blockIdx.y == 1) ? Wq : Wv);
    unsigned short* Wtm = Wt + blockIdx.y * (HH * CC);
    const int c0 = blockIdx.x * 64;
#pragma unroll
    for (int i = 0; i < 16; ++i) {
        int id = threadIdx.x + i * 256;         // 0..4095
        int c = id >> 6, h = id & 63;
        tile[c][h] = f2bf(Wm[(c0 + c) * HH + h]);   // coalesced read
    }
    __syncthreads();
#pragma unroll
    for (int i = 0; i < 16; ++i) {
        int id = threadIdx.x + i * 256;
        int h = id >> 6, c = id & 63;
        Wtm[h * CC + c0 + c] = tile[c][h];      // coalesced write
    }
}

// ---------------------------------------------------------------- kernel 2
// QKV projection: [32768,384]x[384,64] x3 with 16x16x32 bf16 MFMA.
// 512 thr = 2 wave-groups x 4 waves; group g accumulates c in [192g,192g+192),
// partials combined in LDS. All 12 x-loads hoisted for MLP. k and vt written
// in MFMA fragment layouts.
__global__ __launch_bounds__(512, 4) void qkv_kernel(
        const float* __restrict__ x,
        const unsigned short* __restrict__ Wt,     // [3][64][384] bf16
        unsigned short* __restrict__ q_ws,         // [32768][64] row-major, pre-scaled
        unsigned short* __restrict__ k_ws,         // fragment layout
        unsigned short* __restrict__ vt_ws) {      // fragment layout
    __shared__ __align__(16) f32x4 xacc[256 * 13];              // 53248 B
    __shared__ __align__(16) unsigned short vtile[64][72];      //  9216 B

    const int lane = threadIdx.x & 63;
    const int wv8  = threadIdx.x >> 6;     // 0..7
    const int grp  = wv8 >> 2;             // wave-group 0/1
    const int wg   = wv8 & 3;              // wave within group
    const int g256 = threadIdx.x & 255;    // thread id within group
    const int l15  = lane & 15;
    const int quad = lane >> 4;
    const int rb   = blockIdx.x * 64;
    const int row  = rb + wg * 16 + l15;           // A-frag m index

    // ---- hoisted x loads: 12 independent float4 in flight ----
    const float* xbase = x + (long)row * CC + grp * 192 + quad * 8;
    float4 xr[12];
#pragma unroll
    for (int i = 0; i < 6; ++i) {
        xr[2 * i]     = *reinterpret_cast<const float4*>(xbase + i * 32);
        xr[2 * i + 1] = *reinterpret_cast<const float4*>(xbase + i * 32 + 4);
    }
    bf16x8 a[6];
#pragma unroll
    for (int i = 0; i < 6; ++i) {
        a[i][0] = (__bf16)xr[2 * i].x;     a[i][1] = (__bf16)xr[2 * i].y;
        a[i][2] = (__bf16)xr[2 * i].z;     a[i][3] = (__bf16)xr[2 * i].w;
        a[i][4] = (__bf16)xr[2 * i + 1].x; a[i][5] = (__bf16)xr[2 * i + 1].y;
        a[i][6] = (__bf16)xr[2 * i + 1].z; a[i][7] = (__bf16)xr[2 * i + 1].w;
    }

    f32x4 acc[3][4];
    const f32x4 zero = {0.f, 0.f, 0.f, 0.f};
#pragma unroll
    for (int m = 0; m < 3; ++m)
#pragma unroll
        for (int nt = 0; nt < 4; ++nt) acc[m][nt] = zero;

#pragma unroll
    for (int i = 0; i < 6; ++i) {
        const int gcoff = grp * 192 + i * 32 + quad * 8;
#pragma unroll
        for (int m = 0; m < 3; ++m) {
            const unsigned short* wtm = Wt + m * (HH * CC);
#pragma unroll
            for (int nt = 0; nt < 4; ++nt) {
                bf16x8 bfr = *reinterpret_cast<const bf16x8*>(
                    wtm + (nt * 16 + l15) * CC + gcoff);
                acc[m][nt] = __builtin_amdgcn_mfma_f32_16x16x32_bf16(
                    a[i], bfr, acc[m][nt], 0, 0, 0);
            }
        }
    }

    // combine the two groups' partials through LDS
    const int cidx = g256 * 13;
    if (grp == 1) {
#pragma unroll
        for (int m = 0; m < 3; ++m)
#pragma unroll
            for (int nt = 0; nt < 4; ++nt)
                xacc[cidx + m * 4 + nt] = acc[m][nt];
    }
    __syncthreads();

    if (grp == 0) {
#pragma unroll
        for (int m = 0; m < 3; ++m)
#pragma unroll
            for (int nt = 0; nt < 4; ++nt)
                acc[m][nt] += xacc[cidx + m * 4 + nt];

        // Epilogue. C-layout: acc[m][nt][r] = out[local row quad*4+r][h = nt*16+l15]
        const int rt = (rb >> 4) + wg;             // global 16-row tile index
#pragma unroll
        for (int nt = 0; nt < 4; ++nt) {
            const int h  = nt * 16 + l15;
            const int c8 = h >> 3;
            const int jj = h & 7;
#pragma unroll
            for (int r = 0; r < 4; ++r) {
                const int gr = rb + wg * 16 + quad * 4 + r;
                const int ii = quad * 4 + r;       // row within 16-tile
                k_ws[((rt * 8 + c8) * 16 + ii) * 8 + jj] = f2bf(acc[0][nt][r]);
                q_ws[gr * HH + h] = f2bf(acc[1][nt][r] * QSCALE);
                vtile[h][ii + wg * 16] = f2bf(acc[2][nt][r]);
            }
        }
    }
    __syncthreads();
    // vt fragment store: chunk id = (dt*8+sc)*16+ii, perfectly coalesced.
    {
        int id = threadIdx.x;                      // 0..511
        int dt = id >> 7, sc = (id >> 4) & 7, ii = id & 15;
        unsigned short* dst = vt_ws + (long)(rb >> 6) * 4096
                              + (dt * 8 + sc) * 128 + ii * 8;
        *reinterpret_cast<uint4*>(dst) =
            *reinterpret_cast<const uint4*>(&vtile[dt * 16 + ii][sc * 8]);
    }
}

// ---------------------------------------------------------------- kernel 3
// Flash attention. 256 blocks x 1024 thr; block (p,b) does q-tile A=63-p
// then B=p (65 k-tiles constant). 16 waves = 4 groups x 4 waves; group g
// takes tiles t = 4j+g of the current phase. Barrier-free k-loop; merge +
// store per phase (keeps live VGPRs ~127).
__global__ __launch_bounds__(1024, 4) void attn_kernel(
        const unsigned short* __restrict__ q_ws,
        const unsigned short* __restrict__ k_ws,   // fragment layout
        const unsigned short* __restrict__ vt_ws,  // fragment layout
        float* __restrict__ out) {
    // P: per-wave 16 rows x 64 s, stride 64, XOR-swizzled (s ^ (q&7)<<3).
    __shared__ __align__(16) unsigned short P_lds[16 * 16 * 64]; // 32768 B
    __shared__ __align__(16) float xchg[64 * 65];                // 16640 B
    __shared__ float mx1[64], lx1[64];

    const int lane = threadIdx.x & 63;
    const int wv16 = threadIdx.x >> 6;     // 0..15
    const int grp  = wv16 >> 2;            // wave-group 0..3
    const int wg   = wv16 & 3;             // wave within group
    const int l15  = lane & 15;
    const int quad = lane >> 4;

    const int bid = blockIdx.x;
    const int b   = bid & 7;               // batch <-> XCD affinity
    const int p   = bid >> 3;              // 0..31

    const f32x4 zero = {0.f, 0.f, 0.f, 0.f};
    const int pbase = wv16 * 1024 + l15 * 64;      // this lane's P row base
    const int pxor  = (l15 & 7) << 3;              // bank swizzle

    // -------- one k-tile of phase with q-tile `qt` --------
    auto do_tile = [&](int t, int qt, int qrow,
                       const bf16x8& qf0, const bf16x8& qf1,
                       f32x4* o, float& mprev, float& lsum) {
        const int s0 = t * 64;
        const unsigned short* ktile = k_ws + ((long)((b * TT + s0) >> 4)) * 1024;
        const unsigned short* vtile = vt_ws + ((long)((b * TT + s0) >> 6)) * 4096;

        bf16x8 ka0[4], ka1[4];
#pragma unroll
        for (int st = 0; st < 4; ++st) {
            ka0[st] = *reinterpret_cast<const bf16x8*>(
                ktile + ((st * 8 + quad) * 16 + l15) * 8);
            ka1[st] = *reinterpret_cast<const bf16x8*>(
                ktile + ((st * 8 + 4 + quad) * 16 + l15) * 8);
        }
        bf16x8 vb0[4], vb1[4];
#pragma unroll
        for (int dt = 0; dt < 4; ++dt) {
            vb0[dt] = *reinterpret_cast<const bf16x8*>(
                vtile + dt * 1024 + quad * 128 + l15 * 8);
            vb1[dt] = *reinterpret_cast<const bf16x8*>(
                vtile + dt * 1024 + (4 + quad) * 128 + l15 * 8);
        }

        f32x4 sc[4];
#pragma unroll
        for (int st = 0; st < 4; ++st) {
            f32x4 z = zero;
            z = __builtin_amdgcn_mfma_f32_16x16x32_bf16(ka0[st], qf0, z, 0, 0, 0);
            z = __builtin_amdgcn_mfma_f32_16x16x32_bf16(ka1[st], qf1, z, 0, 0, 0);
            sc[st] = z;
        }

        if (t == qt) {                    // causal mask, diagonal tile only
#pragma unroll
            for (int st = 0; st < 4; ++st)
#pragma unroll
                for (int r = 0; r < 4; ++r) {
                    int sg = s0 + st * 16 + quad * 4 + r;
                    if (sg > qrow) sc[st][r] = -1e30f;
                }
        }

        float mloc = -1e30f;
#pragma unroll
        for (int st = 0; st < 4; ++st)
#pragma unroll
            for (int r = 0; r < 4; ++r) mloc = fmaxf(mloc, sc[st][r]);
        mloc = fmaxf(mloc, __shfl_xor(mloc, 16));
        mloc = fmaxf(mloc, __shfl_xor(mloc, 32));
        const float mnew = fmaxf(mprev, mloc);
        const unsigned long long anych = __ballot(mnew > mprev);
        float alpha = 1.0f;
        if (anych) alpha = EXP2(mprev - mnew);

        float psum = 0.f;
#pragma unroll
        for (int st = 0; st < 4; ++st) {
            union { unsigned short us[4]; uint2 u2; } pk;
#pragma unroll
            for (int r = 0; r < 4; ++r) {
                float pv = EXP2(sc[st][r] - mnew);
                psum += pv;
                pk.us[r] = f2bf(pv);
            }
            *reinterpret_cast<uint2*>(
                &P_lds[pbase + ((st * 16 + quad * 4) ^ pxor)]) = pk.u2;
        }
        psum += __shfl_xor(psum, 16);
        psum += __shfl_xor(psum, 32);
        lsum = lsum * alpha + psum;
        mprev = mnew;

        if (anych) {
            float ar[4];
#pragma unroll
            for (int r = 0; r < 4; ++r) ar[r] = __shfl(alpha, quad * 4 + r);
#pragma unroll
            for (int dt = 0; dt < 4; ++dt)
#pragma unroll
                for (int r = 0; r < 4; ++r) o[dt][r] *= ar[r];
        }

        LDS_ROUNDTRIP_FENCE();   // wave-local P write->read ordering

        bf16x8 pf0 = *reinterpret_cast<const bf16x8*>(
            &P_lds[pbase + ((quad * 8) ^ pxor)]);
        bf16x8 pf1 = *reinterpret_cast<const bf16x8*>(
            &P_lds[pbase + ((32 + quad * 8) ^ pxor)]);
#pragma unroll
        for (int dt = 0; dt < 4; ++dt) {
            o[dt] = __builtin_amdgcn_mfma_f32_16x16x32_bf16(pf0, vb0[dt], o[dt], 0, 0, 0);
            o[dt] = __builtin_amdgcn_mfma_f32_16x16x32_bf16(pf1, vb1[dt], o[dt], 0, 0, 0);
        }
    };

    // -------- merge groups 1..3 into group 0, then store q-tile `qt` --------
    auto merge_store = [&](int qt, f32x4* o, float& mprev, float& lsum) {
        for (int rr = 1; rr < 4; ++rr) {
            __syncthreads();
            if (grp == rr) {
                if (quad == 0) { mx1[wg * 16 + l15] = mprev; lx1[wg * 16 + l15] = lsum; }
#pragma unroll
                for (int dt = 0; dt < 4; ++dt)
#pragma unroll
                    for (int r = 0; r < 4; ++r)
                        xchg[(wg * 16 + quad * 4 + r) * 65 + dt * 16 + l15] = o[dt][r];
            }
            __syncthreads();
            if (grp == 0) {
#pragma unroll
                for (int r = 0; r < 4; ++r) {
                    const int row = wg * 16 + quad * 4 + r;
                    const float m0r = __shfl(mprev, quad * 4 + r);
                    const float m1r = mx1[row];
                    const float ms  = fmaxf(m0r, m1r);
                    const float w0  = EXP2(m0r - ms);
                    const float w1  = EXP2(m1r - ms);
#pragma unroll
                    for (int dt = 0; dt < 4; ++dt)
                        o[dt][r] = o[dt][r] * w0 + xchg[row * 65 + dt * 16 + l15] * w1;
                }
                const float m1l = mx1[wg * 16 + l15];
                const float msl = fmaxf(mprev, m1l);
                lsum = EXP2(mprev - msl) * lsum + EXP2(m1l - msl) * lx1[wg * 16 + l15];
                mprev = msl;
            }
        }
        if (grp == 0) {
            float rl[4];
#pragma unroll
            for (int r = 0; r < 4; ++r) rl[r] = 1.0f / __shfl(lsum, quad * 4 + r);
            const int orow = qt * 64 + wg * 16 + quad * 4;
#pragma unroll
            for (int dt = 0; dt < 4; ++dt)
#pragma unroll
                for (int r = 0; r < 4; ++r)
                    out[(long)(b * TT + orow + r) * HH + dt * 16 + l15] = o[dt][r] * rl[r];
        }
        __syncthreads();   // xchg/mx1 reusable by next phase
    };

    // ---------------- phase A: q-tile 63-p ----------------
    {
        const int qt = 63 - p;
        const int qrow = qt * 64 + wg * 16 + l15;
        const unsigned short* qbase = q_ws + (b * TT + qrow) * HH;
        const bf16x8 qf0 = *reinterpret_cast<const bf16x8*>(qbase + quad * 8);
        const bf16x8 qf1 = *reinterpret_cast<const bf16x8*>(qbase + 32 + quad * 8);
        f32x4 o[4];
#pragma unroll
        for (int dt = 0; dt < 4; ++dt) o[dt] = zero;
        float mprev = -1e30f, lsum = 0.f;
        for (int t = grp; t <= qt; t += 4)
            do_tile(t, qt, qrow, qf0, qf1, o, mprev, lsum);
        merge_store(qt, o, mprev, lsum);
    }

    // ---------------- phase B: q-tile p ----------------
    {
        const int qt = p;
        const int qrow = qt * 64 + wg * 16 + l15;
        const unsigned short* qbase = q_ws + (b * TT + qrow) * HH;
        const bf16x8 qf0 = *reinterpret_cast<const bf16x8*>(qbase + quad * 8);
        const bf16x8 qf1 = *reinterpret_cast<const bf16x8*>(qbase + 32 + quad * 8);
        f32x4 o[4];
#pragma unroll
        for (int dt = 0; dt < 4; ++dt) o[dt] = zero;
        float mprev = -1e30f, lsum = 0.f;
        for (int t = grp; t <= qt; t += 4)
            do_tile(t, qt, qrow, qf0, qf1, o, mprev, lsum);
        merge_store(qt, o, mprev, lsum);
    }
}

// ---------------------------------------------------------------- launch
extern "C" void kernel_launch(void* const* d_in, const int* in_sizes, int n_in,
                              void* d_out, int out_size, void* d_ws, size_t ws_size,
                              hipStream_t stream) {
    const float* x  = (const float*)d_in[0];
    const float* Wk = (const float*)d_in[1];
    const float* Wq = (const float*)d_in[2];
    const float* Wv = (const float*)d_in[3];
    float* out = (float*)d_out;

    char* ws = (char*)d_ws;
    unsigned short* Wt    = (unsigned short*)(ws);                         // 147456 B
    unsigned short* q_ws  = (unsigned short*)(ws + 147456);                // 4 MiB
    unsigned short* k_ws  = (unsigned short*)(ws + 147456 + 4194304);      // 4 MiB
    unsigned short* vt_ws = (unsigned short*)(ws + 147456 + 2 * 4194304);  // 4 MiB

    wtrans_kernel<<<dim3(6, 3), 256, 0, stream>>>(Wk, Wq, Wv, Wt);
    qkv_kernel<<<NROW / 64, 512, 0, stream>>>(x, Wt, q_ws, k_ws, vt_ws);
    attn_kernel<<<(TT / 128) * BB, 1024, 0, stream>>>(q_ws, k_ws, vt_ws, out);
}